// Round 1
// baseline (65.525 us; speedup 1.0000x reference)
//
#include <hip/hip_runtime.h>
#include <math.h>

// Problem constants (from reference): B=64, F=2048, D=64.
#define FNUM 2048
#define DDIM 64
#define BATCH 64

// Identity: sum_{f,g} (e_f . e_g) = ||sum_f e_f||^2 with e_f = x_f * V_f.
// pred[b] = sigmoid(gb + sum_f x[b,f]*bias[f] + sum_d (sum_f x[b,f]*V[f,d])^2).
//
// v3 (floor probe): v2 measured 64.6 us, but all top-5 rocprof dispatches are
// 268MB harness poison-fills at ~40 us / 85% HBM peak; the kernel itself is
// modeled at ~3 us. This version removes the remaining exposed-latency costs:
//  - no LDS staging of the data row (global broadcast loads, L1-resident),
//    so embed loads issue immediately with no staging barrier ahead of them;
//  - 64->16 parallel fold of the partial-S rows before the wave-0 reduce.
// If dur_us does not move, the measurement is harness-floor-bound.
__global__ __launch_bounds__(1024)
void KTM_22110491640579_kernel(const float* __restrict__ data,   // B x F
                               const float* __restrict__ embed,  // F x D
                               const float* __restrict__ bias,   // F
                               const float* __restrict__ gbias,  // 1
                               float* __restrict__ out)          // B
{
    const int b = blockIdx.x;
    const int t = threadIdx.x;

    __shared__ float red[64][64];      // 16 KB: partial S rows, red[fbase][d]
    __shared__ float lin_red[16];      // per-wave linear-term partials

    const float* __restrict__ xrow = data + (size_t)b * FNUM;

    // S[d] = sum_f x[f] * V[f][d], f split 64-way across fbase = t>>4.
    // Within a wave the x load touches 4 consecutive floats (one 16B segment,
    // broadcast to 16 lanes each); embed load is a fully coalesced float4.
    const int fbase = t >> 4;   // 0..63
    const int dg    = t & 15;   // 0..15 (d = 4*dg .. 4*dg+3)
    const float4* E4 = (const float4*)embed;  // FNUM rows x 16 float4
    float4 acc = make_float4(0.f, 0.f, 0.f, 0.f);
    #pragma unroll 8
    for (int i = 0; i < FNUM / 64; ++i) {     // 32 iterations
        const int f = i * 64 + fbase;
        const float x = xrow[f];
        const float4 e = E4[f * 16 + dg];
        acc.x += x * e.x;
        acc.y += x * e.y;
        acc.z += x * e.z;
        acc.w += x * e.w;
    }
    ((float4*)&red[fbase][0])[dg] = acc;

    // Linear term: lin = sum_f x[f]*bias[f]; 2 elems/thread, wave-shuffle reduce.
    {
        float lacc = xrow[t] * bias[t] + xrow[t + 1024] * bias[t + 1024];
        #pragma unroll
        for (int off = 32; off > 0; off >>= 1)
            lacc += __shfl_down(lacc, off, 64);
        if ((t & 63) == 0) lin_red[t >> 6] = lacc;
    }
    __syncthreads();

    // Parallel fold 64 rows -> 16 rows: thread t handles (r = t>>6, c = t&63).
    // Per wave: same r, c spans 0..63 -> 2 lanes/bank (free on CDNA4).
    {
        const int r = t >> 6;   // 0..15
        const int c = t & 63;
        red[r][c] += red[r + 16][c] + red[r + 32][c] + red[r + 48][c];
    }
    __syncthreads();

    // Final reduce in wave 0: S_d = sum over 16 folded rows, square, + lin, sigmoid.
    if (t < 64) {
        float s = 0.f;
        #pragma unroll
        for (int r = 0; r < 16; ++r)
            s += red[r][t];
        float val = s * s;
        if (t < 16) val += lin_red[t];
        #pragma unroll
        for (int off = 32; off > 0; off >>= 1)
            val += __shfl_down(val, off, 64);
        if (t == 0) {
            const float z = gbias[0] + val;
            out[b] = 1.0f / (1.0f + expf(-z));
        }
    }
}

extern "C" void kernel_launch(void* const* d_in, const int* in_sizes, int n_in,
                              void* d_out, int out_size, void* d_ws, size_t ws_size,
                              hipStream_t stream) {
    const float* data  = (const float*)d_in[0];  // (64, 2048)
    const float* embed = (const float*)d_in[1];  // (2048, 64)
    const float* bias  = (const float*)d_in[2];  // (2048, 1)
    const float* gb    = (const float*)d_in[3];  // (1, 1)
    float* out = (float*)d_out;                  // (64,)

    KTM_22110491640579_kernel<<<BATCH, 1024, 0, stream>>>(data, embed, bias, gb, out);
}